// Round 1
// baseline (175.047 us; speedup 1.0000x reference)
//
#include <hip/hip_runtime.h>
#include <hip/hip_bf16.h>

#define F_DIM 256
#define N_DIM 128
#define B_DIM 4096
#define BM 256   // batch rows per main block

typedef float f32x4 __attribute__((ext_vector_type(4)));
typedef short s16x8 __attribute__((ext_vector_type(8)));

__device__ __forceinline__ unsigned short f2bf(float f) {
  union { float f; unsigned u; } v; v.f = f;
  unsigned r = v.u + 0x7fffu + ((v.u >> 16) & 1u);   // RNE
  return (unsigned short)(r >> 16);
}

__device__ __forceinline__ void gload16(const void* g, void* l) {
  __builtin_amdgcn_global_load_lds(
      (const __attribute__((address_space(1))) unsigned int*)g,
      (__attribute__((address_space(3))) unsigned int*)l, 16, 0, 0);
}

// ---------------------------------------------------------------------------
// prep_w: w2,w3 (F,128,128) fp32 [i][o] -> per-feature bf16 W^T [o][i],
// row stride 256B, stored PRE-SWIZZLED: dword (o*64+i2) lands at
// (o*64+i2) ^ ((o&7)<<2)  (== byte ^ ((o&7)<<4)).  Matrices 0..255 = w2,
// 256..511 = w3.  Linear global_load_lds then reproduces the swizzled LDS.
// ---------------------------------------------------------------------------
__global__ void prep_w(const float* __restrict__ w2, const float* __restrict__ w3,
                       unsigned int* __restrict__ wTs) {
  __shared__ float tile[128 * 130];   // [o][i], padded stride vs bank conflicts
  int m = blockIdx.x;
  const float* src = (m < 256) ? (w2 + (size_t)m * 16384)
                               : (w3 + (size_t)(m - 256) * 16384);
  int t = threadIdx.x;  // 256
  for (int k = 0; k < 64; ++k) {
    int idx = k * 256 + t;            // coalesced read of [i][o]
    int i = idx >> 7, o = idx & 127;
    tile[o * 130 + i] = src[idx];
  }
  __syncthreads();
  unsigned int* dst = wTs + (size_t)m * 8192;
  for (int k = 0; k < 32; ++k) {
    int idx = k * 256 + t;            // logical dword id: o = idx>>6, i2 = idx&63
    int o = idx >> 6, i2 = idx & 63;
    unsigned pk = (unsigned)f2bf(tile[o * 130 + 2 * i2]) |
                  ((unsigned)f2bf(tile[o * 130 + 2 * i2 + 1]) << 16);
    dst[(o * 64 + i2) ^ ((o & 7) << 2)] = pk;
  }
}

// ---------------------------------------------------------------------------
// prep_x: x (B,F) -> xT (F,B) fp32, tiled transpose
// ---------------------------------------------------------------------------
__global__ void prep_x(const float* __restrict__ x, float* __restrict__ xT) {
  __shared__ float tile[64][65];
  int btile = blockIdx.x & 63;
  int ftile = blockIdx.x >> 6;
  int t = threadIdx.x;  // 256
  for (int k = 0; k < 16; ++k) {
    int idx = k * 256 + t;
    int r = idx >> 6, c = idx & 63;
    tile[r][c] = x[(size_t)(btile * 64 + r) * F_DIM + ftile * 64 + c];
  }
  __syncthreads();
  for (int k = 0; k < 16; ++k) {
    int idx = k * 256 + t;
    int fr = idx >> 6, br = idx & 63;
    xT[(size_t)(ftile * 64 + fr) * B_DIM + btile * 64 + br] = tile[br][fr];
  }
}

// ---------------------------------------------------------------------------
// mlp_main: one block = (feature f, 256-row batch tile).
// 512 thr = 8 waves, wave grid 4x2, wave tile 64x64, mfma 16x16x32 bf16.
// LDS: H (256x128 bf16, swizzled) + W2,W3 (128x128 bf16, swizzled) + yb.
// ---------------------------------------------------------------------------
__global__ __launch_bounds__(512, 2) void mlp_main(
    const float* __restrict__ xT, const float* __restrict__ w1,
    const float* __restrict__ b1, const float* __restrict__ b2,
    const float* __restrict__ b3, const float* __restrict__ w4,
    const float* __restrict__ b4, const unsigned int* __restrict__ wTs,
    float* __restrict__ xp) {
  __shared__ __align__(16) char Hb[BM * 256];        // 64 KiB
  __shared__ __align__(16) char Wb[2][128 * 256];    // 2 x 32 KiB
  __shared__ float yb[2][BM];                        // per-wc layer4 partials

  const int f  = blockIdx.x >> 4;
  const int b0 = (blockIdx.x & 15) * BM;
  const int t  = threadIdx.x;
  const int lane = t & 63;
  const int w  = t >> 6;

  // ---- stage W2[f], W3[f] (pre-swizzled bf16) -> LDS, linear copy ----
  {
    const char* s2 = (const char*)(wTs + (size_t)f * 8192);
    const char* s3 = (const char*)(wTs + (size_t)(256 + f) * 8192);
#pragma unroll
    for (int c = 0; c < 4; ++c) {
      int off = (w * 4 + c) * 1024;
      gload16(s2 + off + lane * 16, &Wb[0][off]);
    }
#pragma unroll
    for (int c = 0; c < 4; ++c) {
      int off = (w * 4 + c) * 1024;
      gload16(s3 + off + lane * 16, &Wb[1][off]);
    }
  }

  // ---- layer 1: H1[r][n] = relu(x[r]*w1[n] + b1[n]), bf16 pair writes ----
  {
    int n2 = t & 63;                 // column pair 2*n2, 2*n2+1
    int r0 = (t >> 6) * 32;          // 32 rows per wave-slice
    float w1a = w1[f * N_DIM + 2 * n2], w1b = w1[f * N_DIM + 2 * n2 + 1];
    float c1a = b1[f * N_DIM + 2 * n2], c1b = b1[f * N_DIM + 2 * n2 + 1];
    const float* xcol = xT + (size_t)f * B_DIM + b0;
#pragma unroll 8
    for (int r = r0; r < r0 + 32; ++r) {
      float xv = xcol[r];            // wave-uniform -> scalar load
      unsigned pk = (unsigned)f2bf(fmaxf(xv * w1a + c1a, 0.f)) |
                    ((unsigned)f2bf(fmaxf(xv * w1b + c1b, 0.f)) << 16);
      *(unsigned*)(Hb + r * 256 + ((4 * n2) ^ ((r & 7) << 4))) = pk;
    }
  }
  __syncthreads();   // drains global_load_lds (W2+W3) + H1 writes

  const int wr = w >> 1, wc = w & 1;
  const int m_base = wr * 64, n_base = wc * 64;
  const int r16 = lane & 15, g = lane >> 4;

  f32x4 acc[4][4];

  // ================= layer 2: H2 = relu(H1 @ W2 + b2) =================
#pragma unroll
  for (int mt = 0; mt < 4; ++mt)
#pragma unroll
    for (int nt = 0; nt < 4; ++nt) acc[mt][nt] = f32x4{0.f, 0.f, 0.f, 0.f};

#pragma unroll 2
  for (int kk = 0; kk < 4; ++kk) {
    int kb = kk * 64 + g * 16;       // byte col of this lane's 8 k-elems
    s16x8 a[4], bb[4];
#pragma unroll
    for (int mt = 0; mt < 4; ++mt) {
      int row = m_base + mt * 16 + r16;
      a[mt] = *(const s16x8*)(Hb + row * 256 + (kb ^ ((row & 7) << 4)));
    }
#pragma unroll
    for (int nt = 0; nt < 4; ++nt) {
      int row = n_base + nt * 16 + r16;
      bb[nt] = *(const s16x8*)(Wb[0] + row * 256 + (kb ^ ((row & 7) << 4)));
    }
#pragma unroll
    for (int mt = 0; mt < 4; ++mt)
#pragma unroll
      for (int nt = 0; nt < 4; ++nt)
        acc[mt][nt] = __builtin_amdgcn_mfma_f32_16x16x32_bf16(a[mt], bb[nt],
                                                              acc[mt][nt], 0, 0, 0);
  }
  __syncthreads();   // everyone done READING H1 before overwrite

#pragma unroll
  for (int nt = 0; nt < 4; ++nt) {
    int col = n_base + nt * 16 + r16;
    float bias = b2[f * N_DIM + col];
#pragma unroll
    for (int mt = 0; mt < 4; ++mt)
#pragma unroll
      for (int i = 0; i < 4; ++i) {
        int row = m_base + mt * 16 + 4 * g + i;
        *(unsigned short*)(Hb + row * 256 + ((2 * col) ^ ((row & 7) << 4))) =
            f2bf(fmaxf(acc[mt][nt][i] + bias, 0.f));
      }
  }
  __syncthreads();   // H2 visible

  // ================= layer 3: H3 = relu(H2 @ W3 + b3) (stays in regs) ====
#pragma unroll
  for (int mt = 0; mt < 4; ++mt)
#pragma unroll
    for (int nt = 0; nt < 4; ++nt) acc[mt][nt] = f32x4{0.f, 0.f, 0.f, 0.f};

#pragma unroll 2
  for (int kk = 0; kk < 4; ++kk) {
    int kb = kk * 64 + g * 16;
    s16x8 a[4], bb[4];
#pragma unroll
    for (int mt = 0; mt < 4; ++mt) {
      int row = m_base + mt * 16 + r16;
      a[mt] = *(const s16x8*)(Hb + row * 256 + (kb ^ ((row & 7) << 4)));
    }
#pragma unroll
    for (int nt = 0; nt < 4; ++nt) {
      int row = n_base + nt * 16 + r16;
      bb[nt] = *(const s16x8*)(Wb[1] + row * 256 + (kb ^ ((row & 7) << 4)));
    }
#pragma unroll
    for (int mt = 0; mt < 4; ++mt)
#pragma unroll
      for (int nt = 0; nt < 4; ++nt)
        acc[mt][nt] = __builtin_amdgcn_mfma_f32_16x16x32_bf16(a[mt], bb[nt],
                                                              acc[mt][nt], 0, 0, 0);
  }

  // ================= layer 4 (fp32): y = relu(H3)·w4, per-row reduce =====
  float p[4][4];
#pragma unroll
  for (int mt = 0; mt < 4; ++mt)
#pragma unroll
    for (int i = 0; i < 4; ++i) p[mt][i] = 0.f;

#pragma unroll
  for (int nt = 0; nt < 4; ++nt) {
    int col = n_base + nt * 16 + r16;
    float bias = b3[f * N_DIM + col];
    float wv   = w4[f * N_DIM + col];
#pragma unroll
    for (int mt = 0; mt < 4; ++mt)
#pragma unroll
      for (int i = 0; i < 4; ++i)
        p[mt][i] += fmaxf(acc[mt][nt][i] + bias, 0.f) * wv;
  }
  // sum the 16 lanes of each k-group (they hold the 16 cols of each row set)
#pragma unroll
  for (int mask = 1; mask <= 8; mask <<= 1)
#pragma unroll
    for (int mt = 0; mt < 4; ++mt)
#pragma unroll
      for (int i = 0; i < 4; ++i)
        p[mt][i] += __shfl_xor(p[mt][i], mask, 64);

  if (r16 == 0) {
#pragma unroll
    for (int mt = 0; mt < 4; ++mt)
#pragma unroll
      for (int i = 0; i < 4; ++i)
        yb[wc][m_base + mt * 16 + 4 * g + i] = p[mt][i];
  }
  __syncthreads();

  if (t < BM) {
    xp[(size_t)f * B_DIM + b0 + t] = yb[0][t] + yb[1][t] + b4[f];
  }
}

// ---------------------------------------------------------------------------
// final_reduce: out[b] = lr_b + sum_f xp[f][b] * lr_w[f]
// ---------------------------------------------------------------------------
__global__ void final_reduce(const float* __restrict__ xp,
                             const float* __restrict__ lr_w,
                             const float* __restrict__ lr_b,
                             float* __restrict__ out) {
  __shared__ float lw[F_DIM];
  __shared__ float part[4][256];
  int t = threadIdx.x;   // 1024
  if (t < F_DIM) lw[t] = lr_w[t];
  __syncthreads();
  int q = t >> 8, bl = t & 255;
  int b = blockIdx.x * 256 + bl;
  float acc = 0.f;
#pragma unroll 4
  for (int j = 0; j < 64; ++j) {
    int ff = q * 64 + j;
    acc += xp[(size_t)ff * B_DIM + b] * lw[ff];
  }
  part[q][bl] = acc;
  __syncthreads();
  if (q == 0)
    out[b] = part[0][bl] + part[1][bl] + part[2][bl] + part[3][bl] + lr_b[0];
}

// ---------------------------------------------------------------------------
extern "C" void kernel_launch(void* const* d_in, const int* in_sizes, int n_in,
                              void* d_out, int out_size, void* d_ws, size_t ws_size,
                              hipStream_t stream) {
  (void)in_sizes; (void)n_in; (void)out_size; (void)ws_size;
  const float* x    = (const float*)d_in[0];
  const float* w1   = (const float*)d_in[1];
  const float* b1   = (const float*)d_in[2];
  const float* w2   = (const float*)d_in[3];
  const float* b2   = (const float*)d_in[4];
  const float* w3   = (const float*)d_in[5];
  const float* b3   = (const float*)d_in[6];
  const float* w4   = (const float*)d_in[7];
  const float* b4   = (const float*)d_in[8];
  const float* lr_w = (const float*)d_in[9];
  const float* lr_b = (const float*)d_in[10];
  float* out = (float*)d_out;

  // ws layout: wTs 16 MiB | xT 4 MiB | xp 4 MiB   (24 MiB total)
  char* ws = (char*)d_ws;
  unsigned int* wTs = (unsigned int*)ws;
  float* xT = (float*)(ws + (16u << 20));
  float* xp = (float*)(ws + (16u << 20) + (4u << 20));

  prep_w<<<512, 256, 0, stream>>>(w2, w3, wTs);
  prep_x<<<256, 256, 0, stream>>>(x, xT);
  mlp_main<<<4096, 512, 0, stream>>>(xT, w1, b1, b2, b3, w4, b4, wTs, xp);
  final_reduce<<<16, 1024, 0, stream>>>(xp, lr_w, lr_b, out);
}

// Round 2
// 147.026 us; speedup vs baseline: 1.1906x; 1.1906x over previous
//
#include <hip/hip_runtime.h>
#include <hip/hip_bf16.h>

#define F_DIM 256
#define N_DIM 128
#define B_DIM 4096
#define BM 256   // batch rows per main block

typedef float f32x4v __attribute__((ext_vector_type(4)));
typedef short s16x8 __attribute__((ext_vector_type(8)));
typedef unsigned int u32x2v __attribute__((ext_vector_type(2)));
typedef unsigned int u32x4v __attribute__((ext_vector_type(4)));

__device__ __forceinline__ unsigned short f2bf(float f) {
  union { float f; unsigned u; } v; v.f = f;
  unsigned r = v.u + 0x7fffu + ((v.u >> 16) & 1u);   // RNE
  return (unsigned short)(r >> 16);
}

// packed f32 pair -> bf16x2 dword (compiler fuses casts into v_cvt_pk_bf16_f32)
__device__ __forceinline__ unsigned pk2(float a, float b) {
  union { __hip_bfloat16 h[2]; unsigned u; } v;
  v.h[0] = __float2bfloat16(a);
  v.h[1] = __float2bfloat16(b);
  return v.u;
}

__device__ __forceinline__ void gload16(const void* g, void* l) {
  __builtin_amdgcn_global_load_lds(
      (const __attribute__((address_space(1))) unsigned int*)g,
      (__attribute__((address_space(3))) unsigned int*)l, 16, 0, 0);
}

// ---------------------------------------------------------------------------
// prep_w: w2,w3 (F,128,128) fp32 [i][o] -> per-feature bf16 W^T [o][i],
// row stride 256B, stored PRE-SWIZZLED: dword (o*64+i2) at (o*64+i2)^((o&7)<<2)
// so a linear global_load_lds reproduces the XOR-swizzled LDS image.
// ---------------------------------------------------------------------------
__global__ void prep_w(const float* __restrict__ w2, const float* __restrict__ w3,
                       unsigned int* __restrict__ wTs) {
  __shared__ float tile[128 * 130];
  int m = blockIdx.x;
  const float* src = (m < 256) ? (w2 + (size_t)m * 16384)
                               : (w3 + (size_t)(m - 256) * 16384);
  int t = threadIdx.x;  // 256
  for (int k = 0; k < 64; ++k) {
    int idx = k * 256 + t;
    int i = idx >> 7, o = idx & 127;
    tile[o * 130 + i] = src[idx];
  }
  __syncthreads();
  unsigned int* dst = wTs + (size_t)m * 8192;
  for (int k = 0; k < 32; ++k) {
    int idx = k * 256 + t;
    int o = idx >> 6, i2 = idx & 63;
    unsigned pk = (unsigned)f2bf(tile[o * 130 + 2 * i2]) |
                  ((unsigned)f2bf(tile[o * 130 + 2 * i2 + 1]) << 16);
    dst[(o * 64 + i2) ^ ((o & 7) << 2)] = pk;
  }
}

// ---------------------------------------------------------------------------
// prep_x: x (B,F) -> xT (F,B) fp32
// ---------------------------------------------------------------------------
__global__ void prep_x(const float* __restrict__ x, float* __restrict__ xT) {
  __shared__ float tile[64][65];
  int btile = blockIdx.x & 63;
  int ftile = blockIdx.x >> 6;
  int t = threadIdx.x;  // 256
  for (int k = 0; k < 16; ++k) {
    int idx = k * 256 + t;
    int r = idx >> 6, c = idx & 63;
    tile[r][c] = x[(size_t)(btile * 64 + r) * F_DIM + ftile * 64 + c];
  }
  __syncthreads();
  for (int k = 0; k < 16; ++k) {
    int idx = k * 256 + t;
    int fr = idx >> 6, br = idx & 63;
    xT[(size_t)(ftile * 64 + fr) * B_DIM + btile * 64 + br] = tile[br][fr];
  }
}

// ---------------------------------------------------------------------------
// mlp_main (transposed compute): one block = (feature f, 256-row batch tile).
// D = mfma(A = W^T frag, B = H^T frag) so the C-fragment holds 4 CONSECUTIVE
// NEURONS of one batch row -> vectorized b64 epilogue stores.
// H kept in [batch][neuron] LDS layout; fragment reads are contiguous b128
// with the (row&7)<<4 XOR swizzle on both sides.
// 512 thr = 8 waves, wave grid: wr(2) over neurons(128), wc(4) over batch(256).
// ---------------------------------------------------------------------------
__global__ __launch_bounds__(512, 2) void mlp_main(
    const float* __restrict__ xT, const float* __restrict__ w1,
    const float* __restrict__ b1, const float* __restrict__ b2,
    const float* __restrict__ b3, const float* __restrict__ w4,
    const float* __restrict__ b4, const unsigned int* __restrict__ wTs,
    float* __restrict__ xp) {
  __shared__ __align__(16) char Hb[BM * 256];        // 64 KiB
  __shared__ __align__(16) char Wb[2][128 * 256];    // 2 x 32 KiB
  __shared__ float yb[2][BM];

  const int f  = blockIdx.x >> 4;
  const int b0 = (blockIdx.x & 15) * BM;
  const int t  = threadIdx.x;
  const int lane = t & 63;
  const int w  = t >> 6;

  // ---- stage W2[f], W3[f] (pre-swizzled bf16) -> LDS, linear gload ----
  {
    const char* s2 = (const char*)(wTs + (size_t)f * 8192);
    const char* s3 = (const char*)(wTs + (size_t)(256 + f) * 8192);
#pragma unroll
    for (int c = 0; c < 4; ++c) {
      int off = (w * 4 + c) * 1024;
      gload16(s2 + off + lane * 16, &Wb[0][off]);
    }
#pragma unroll
    for (int c = 0; c < 4; ++c) {
      int off = (w * 4 + c) * 1024;
      gload16(s3 + off + lane * 16, &Wb[1][off]);
    }
  }

  // ---- layer 1: H1[n][o] = relu(x[n]*w1[o] + b1[o]), 8 neurons/thread ----
  {
    const int og = t & 15;           // neuron octet, fixed per thread
    const int nb = t >> 4;           // 0..31
    const float* wp = w1 + f * N_DIM + og * 8;
    const float* bp = b1 + f * N_DIM + og * 8;
    f32x4v w1a = *(const f32x4v*)wp, w1b = *(const f32x4v*)(wp + 4);
    f32x4v b1a = *(const f32x4v*)bp, b1b = *(const f32x4v*)(bp + 4);
    const float* xcol = xT + (size_t)f * B_DIM + b0;
    const int co = og * 16;          // byte col of neuron octet
#pragma unroll
    for (int it = 0; it < 8; ++it) {
      int n = it * 32 + nb;
      float xv = xcol[n];
      u32x4v pk;
      pk[0] = pk2(fmaxf(xv * w1a[0] + b1a[0], 0.f), fmaxf(xv * w1a[1] + b1a[1], 0.f));
      pk[1] = pk2(fmaxf(xv * w1a[2] + b1a[2], 0.f), fmaxf(xv * w1a[3] + b1a[3], 0.f));
      pk[2] = pk2(fmaxf(xv * w1b[0] + b1b[0], 0.f), fmaxf(xv * w1b[1] + b1b[1], 0.f));
      pk[3] = pk2(fmaxf(xv * w1b[2] + b1b[2], 0.f), fmaxf(xv * w1b[3] + b1b[3], 0.f));
      *(u32x4v*)(Hb + n * 256 + (co ^ ((n & 7) << 4))) = pk;
    }
  }
  __syncthreads();   // drains gload_lds (W2+W3) + H1 writes

  const int wr = w & 1, wc = w >> 1;
  const int m_base = wr * 64;        // neuron (output) base
  const int n_base = wc * 64;        // batch base
  const int r16 = lane & 15, g = lane >> 4;
  const int swz = (r16 & 7) << 4;
  const int gx = (g * 16) ^ swz;

  int baseH[4], baseW[4];
#pragma unroll
  for (int i = 0; i < 4; ++i) {
    baseH[i] = (n_base + i * 16 + r16) * 256 + gx;   // B-frag rows: batch
    baseW[i] = (m_base + i * 16 + r16) * 256 + gx;   // A-frag rows: neuron
  }

  f32x4v acc[4][4];

  // ================= layer 2: H2^T = W2^T @ H1^T =================
#pragma unroll
  for (int mt = 0; mt < 4; ++mt)
#pragma unroll
    for (int nt = 0; nt < 4; ++nt) acc[mt][nt] = f32x4v{0.f, 0.f, 0.f, 0.f};

#pragma unroll 2
  for (int kk = 0; kk < 4; ++kk) {
    s16x8 af[4], bf[4];
#pragma unroll
    for (int mt = 0; mt < 4; ++mt)
      af[mt] = *(const s16x8*)(&Wb[0][0] + (baseW[mt] ^ (kk << 6)));
#pragma unroll
    for (int nt = 0; nt < 4; ++nt)
      bf[nt] = *(const s16x8*)(Hb + (baseH[nt] ^ (kk << 6)));
#pragma unroll
    for (int mt = 0; mt < 4; ++mt)
#pragma unroll
      for (int nt = 0; nt < 4; ++nt)
        acc[mt][nt] = __builtin_amdgcn_mfma_f32_16x16x32_bf16(af[mt], bf[nt],
                                                              acc[mt][nt], 0, 0, 0);
  }
  __syncthreads();   // all H1 reads done before overwrite

  // ---- epilogue: H2[n][o] = relu(acc + b2[o]), vectorized b64 stores ----
  {
    const float* b2p = b2 + f * N_DIM + m_base + g * 4;
#pragma unroll
    for (int mt = 0; mt < 4; ++mt) {
      f32x4v bias = *(const f32x4v*)(b2p + mt * 16);
      const int o2 = 2 * (m_base + mt * 16 + g * 4);
#pragma unroll
      for (int nt = 0; nt < 4; ++nt) {
        int n = n_base + nt * 16 + r16;
        f32x4v v = acc[mt][nt];
        u32x2v d;
        d[0] = pk2(fmaxf(v[0] + bias[0], 0.f), fmaxf(v[1] + bias[1], 0.f));
        d[1] = pk2(fmaxf(v[2] + bias[2], 0.f), fmaxf(v[3] + bias[3], 0.f));
        *(u32x2v*)(Hb + n * 256 + (o2 ^ ((n & 7) << 4))) = d;
      }
    }
  }
  __syncthreads();   // H2 visible

  // ================= layer 3: H3^T = W3^T @ H2^T =================
#pragma unroll
  for (int mt = 0; mt < 4; ++mt)
#pragma unroll
    for (int nt = 0; nt < 4; ++nt) acc[mt][nt] = f32x4v{0.f, 0.f, 0.f, 0.f};

#pragma unroll 2
  for (int kk = 0; kk < 4; ++kk) {
    s16x8 af[4], bf[4];
#pragma unroll
    for (int mt = 0; mt < 4; ++mt)
      af[mt] = *(const s16x8*)(&Wb[1][0] + (baseW[mt] ^ (kk << 6)));
#pragma unroll
    for (int nt = 0; nt < 4; ++nt)
      bf[nt] = *(const s16x8*)(Hb + (baseH[nt] ^ (kk << 6)));
#pragma unroll
    for (int mt = 0; mt < 4; ++mt)
#pragma unroll
      for (int nt = 0; nt < 4; ++nt)
        acc[mt][nt] = __builtin_amdgcn_mfma_f32_16x16x32_bf16(af[mt], bf[nt],
                                                              acc[mt][nt], 0, 0, 0);
  }

  // ====== layer 4 (fp32): y[n] = sum_o relu(H3^T[o][n] + b3[o]) * w4[o] ====
  {
    float p[4] = {0.f, 0.f, 0.f, 0.f};
    const float* b3p = b3 + f * N_DIM + m_base + g * 4;
    const float* w4p = w4 + f * N_DIM + m_base + g * 4;
#pragma unroll
    for (int mt = 0; mt < 4; ++mt) {
      f32x4v b3v = *(const f32x4v*)(b3p + mt * 16);
      f32x4v w4v = *(const f32x4v*)(w4p + mt * 16);
#pragma unroll
      for (int nt = 0; nt < 4; ++nt)
#pragma unroll
        for (int i = 0; i < 4; ++i)
          p[nt] += fmaxf(acc[mt][nt][i] + b3v[i], 0.f) * w4v[i];
    }
#pragma unroll
    for (int nt = 0; nt < 4; ++nt) {
      p[nt] += __shfl_xor(p[nt], 16, 64);
      p[nt] += __shfl_xor(p[nt], 32, 64);
    }
    if (g == 0) {
#pragma unroll
      for (int nt = 0; nt < 4; ++nt) yb[wr][n_base + nt * 16 + r16] = p[nt];
    }
  }
  __syncthreads();

  if (t < BM) {
    xp[(size_t)f * B_DIM + b0 + t] = yb[0][t] + yb[1][t] + b4[f];
  }
}

// ---------------------------------------------------------------------------
// final_reduce: out[b] = lr_b + sum_f xp[f][b] * lr_w[f]
// ---------------------------------------------------------------------------
__global__ void final_reduce(const float* __restrict__ xp,
                             const float* __restrict__ lr_w,
                             const float* __restrict__ lr_b,
                             float* __restrict__ out) {
  __shared__ float lw[F_DIM];
  __shared__ float part[4][256];
  int t = threadIdx.x;   // 1024
  if (t < F_DIM) lw[t] = lr_w[t];
  __syncthreads();
  int q = t >> 8, bl = t & 255;
  int b = blockIdx.x * 256 + bl;
  float acc = 0.f;
#pragma unroll 4
  for (int j = 0; j < 64; ++j) {
    int ff = q * 64 + j;
    acc += xp[(size_t)ff * B_DIM + b] * lw[ff];
  }
  part[q][bl] = acc;
  __syncthreads();
  if (q == 0)
    out[b] = part[0][bl] + part[1][bl] + part[2][bl] + part[3][bl] + lr_b[0];
}

// ---------------------------------------------------------------------------
extern "C" void kernel_launch(void* const* d_in, const int* in_sizes, int n_in,
                              void* d_out, int out_size, void* d_ws, size_t ws_size,
                              hipStream_t stream) {
  (void)in_sizes; (void)n_in; (void)out_size; (void)ws_size;
  const float* x    = (const float*)d_in[0];
  const float* w1   = (const float*)d_in[1];
  const float* b1   = (const float*)d_in[2];
  const float* w2   = (const float*)d_in[3];
  const float* b2   = (const float*)d_in[4];
  const float* w3   = (const float*)d_in[5];
  const float* b3   = (const float*)d_in[6];
  const float* w4   = (const float*)d_in[7];
  const float* b4   = (const float*)d_in[8];
  const float* lr_w = (const float*)d_in[9];
  const float* lr_b = (const float*)d_in[10];
  float* out = (float*)d_out;

  // ws layout: wTs 16 MiB | xT 4 MiB | xp 4 MiB
  char* ws = (char*)d_ws;
  unsigned int* wTs = (unsigned int*)ws;
  float* xT = (float*)(ws + (16u << 20));
  float* xp = (float*)(ws + (16u << 20) + (4u << 20));

  prep_w<<<512, 256, 0, stream>>>(w2, w3, wTs);
  prep_x<<<256, 256, 0, stream>>>(x, xT);
  mlp_main<<<4096, 512, 0, stream>>>(xT, w1, b1, b2, b3, w4, b4, wTs, xp);
  final_reduce<<<16, 1024, 0, stream>>>(xp, lr_w, lr_b, out);
}